// Round 1
// baseline (1610.953 us; speedup 1.0000x reference)
//
#include <hip/hip_runtime.h>
#include <hip/hip_bf16.h>
#include <math.h>

#define NV 163842
#define NE 983052

// order-preserving float->uint transform (for descending top-k: larger value -> larger key)
static __device__ __forceinline__ unsigned ordf(float f){
  unsigned u = __float_as_uint(f);
  return (u & 0x80000000u) ? ~u : (u | 0x80000000u);
}

__global__ void fill_f32(float* p, float v, int n){
  int i = blockIdx.x*blockDim.x + threadIdx.x;
  if(i<n) p[i]=v;
}

__global__ void copy_edges(const int* __restrict__ ei, int* __restrict__ src,
                           int* __restrict__ dst, int* __restrict__ valid){
  int i = blockIdx.x*blockDim.x + threadIdx.x;
  if(i<NE){ src[i]=ei[i]; dst[i]=ei[NE+i]; valid[i]=1; }
}

// hw = h @ W, thread computes one output column for 16 consecutive rows (amortizes W reads)
__global__ void matmul16(const float* __restrict__ h, const float* __restrict__ W,
                         float* __restrict__ hw, int n, int Fi, int Fo, int shift){
  long long t = (long long)blockIdx.x*blockDim.x + threadIdx.x;
  int c = (int)(t & (Fo-1));
  int rb = (int)(t >> shift) * 16;
  if(rb >= n) return;
  float acc[16];
  #pragma unroll
  for(int j=0;j<16;j++) acc[j]=0.f;
  int rows = n - rb; if(rows>16) rows=16;
  if(rows==16){
    for(int i=0;i<Fi;i++){
      float w = W[(size_t)i*Fo + c];
      const float* hp = h + (size_t)rb*Fi + i;
      #pragma unroll
      for(int j=0;j<16;j++) acc[j] = fmaf(hp[(size_t)j*Fi], w, acc[j]);
    }
  } else {
    for(int i=0;i<Fi;i++){
      float w = W[(size_t)i*Fo + c];
      const float* hp = h + (size_t)rb*Fi + i;
      for(int j=0;j<rows;j++) acc[j] = fmaf(hp[(size_t)j*Fi], w, acc[j]);
    }
  }
  for(int j=0;j<rows;j++) hw[(size_t)(rb+j)*Fo + c] = acc[j];
}

__global__ void scatter_deg(const int* __restrict__ src, const int* __restrict__ dst,
                            const int* __restrict__ valid, float* __restrict__ deg){
  int e = blockIdx.x*blockDim.x + threadIdx.x;
  if(e<NE && valid[e]) atomicAdd(&deg[dst[e]], 1.0f);
}

__global__ void compute_norm(const int* __restrict__ src, const int* __restrict__ dst,
                             const int* __restrict__ valid, const float* __restrict__ deg,
                             float* __restrict__ enorm){
  int e = blockIdx.x*blockDim.x + threadIdx.x;
  if(e>=NE) return;
  if(valid[e]){
    float a = deg[src[e]]+1.0f, b = deg[dst[e]]+1.0f;
    enorm[e] = (1.0f/sqrtf(a))*(1.0f/sqrtf(b));
  } else enorm[e]=0.f;
}

__global__ void scatter_agg(const int* __restrict__ src, const int* __restrict__ dst,
                            const int* __restrict__ valid, const float* __restrict__ enorm,
                            const float* __restrict__ hw, float* __restrict__ agg,
                            int Fo, int shift){
  long long t = (long long)blockIdx.x*blockDim.x + threadIdx.x;
  int e = (int)(t >> shift);
  if(e >= NE) return;
  if(!valid[e]) return;
  int f = (int)(t & (Fo-1));
  int s = src[e], d = dst[e];
  atomicAdd(&agg[(size_t)d*Fo+f], hw[(size_t)s*Fo+f]*enorm[e]);
}

// h_full = relu(agg + hw/deg_tot + b)  (written in place into agg)
__global__ void finalize(float* __restrict__ agg, const float* __restrict__ hw,
                         const float* __restrict__ deg, const float* __restrict__ b,
                         int n, int Fo, int shift){
  long long t = (long long)blockIdx.x*blockDim.x + threadIdx.x;
  int r = (int)(t >> shift);
  if(r >= n) return;
  int f = (int)(t & (Fo-1));
  float dt = deg[r]+1.0f;
  float v = agg[t] + hw[t]*(1.0f/dt) + b[f];
  agg[t] = v>0.f ? v : 0.f;
}

__global__ void pnorm_kernel(const float* __restrict__ p, int F, float* __restrict__ out){
  float s=0.f;
  for(int f=threadIdx.x; f<F; f+=64) s += p[f]*p[f];
  for(int o=32;o;o>>=1) s += __shfl_down(s,o,64);
  if(threadIdx.x==0) out[0] = sqrtf(s);
}

// score[i] = tanh((h[i,:] . p) / ||p||), one wave per row
__global__ void score_kernel(const float* __restrict__ h, int n, int F,
                             const float* __restrict__ p, const float* __restrict__ pn,
                             float* __restrict__ score){
  int wid = (int)(((long long)blockIdx.x*blockDim.x + threadIdx.x) >> 6);
  int lane = threadIdx.x & 63;
  if(wid>=n) return;
  const float* row = h + (size_t)wid*F;
  float s=0.f;
  for(int f=lane; f<F; f+=64) s = fmaf(row[f], p[f], s);
  for(int o=32;o;o>>=1) s += __shfl_down(s,o,64);
  if(lane==0) score[wid] = tanhf(s / pn[0]);
}

// exact k-th largest (by float value) via 4-pass byte radix select; outputs value-threshold
// (ordf encoding) and q = quota of threshold-equal elements to keep (lowest index first)
__global__ void radix_select(const float* __restrict__ score, int n, int k,
                             unsigned* __restrict__ out_thr, int* __restrict__ out_q){
  __shared__ int hist[256];
  __shared__ unsigned pref;
  __shared__ int rank;
  if(threadIdx.x==0){ pref=0u; rank=k; }
  __syncthreads();
  for(int b=3;b>=0;b--){
    if(threadIdx.x<256) hist[threadIdx.x]=0;
    __syncthreads();
    unsigned p = pref;
    for(int i=threadIdx.x;i<n;i+=blockDim.x){
      unsigned o = ordf(score[i]);
      bool match = (b==3) || (((o ^ p) >> ((b+1)*8)) == 0);
      if(match) atomicAdd(&hist[(o>>(b*8))&255],1);
    }
    __syncthreads();
    if(threadIdx.x==0){
      int running=0; int d;
      for(d=255;d>0;d--){
        if(running + hist[d] >= rank) break;
        running += hist[d];
      }
      pref |= ((unsigned)d) << (b*8);
      rank -= running;
    }
    __syncthreads();
  }
  if(threadIdx.x==0){ out_thr[0]=pref; out_q[0]=rank; }
}

__global__ void sel_blockcount(const float* __restrict__ score, int n,
                               const unsigned* __restrict__ thr,
                               int* __restrict__ blkGt, int* __restrict__ blkEq){
  int i = blockIdx.x*256 + threadIdx.x;
  unsigned vthr = thr[0];
  int gt=0, eq=0;
  if(i<n){ unsigned o=ordf(score[i]); gt = (o>vthr); eq = (o==vthr); }
  unsigned long long bg=__ballot(gt), be=__ballot(eq);
  __shared__ int sg[4], se[4];
  int lane=threadIdx.x&63, w=threadIdx.x>>6;
  if(lane==0){ sg[w]=__popcll(bg); se[w]=__popcll(be); }
  __syncthreads();
  if(threadIdx.x==0){
    int g=0,e=0;
    for(int j=0;j<4;j++){ g+=sg[j]; e+=se[j]; }
    blkGt[blockIdx.x]=g; blkEq[blockIdx.x]=e;
  }
}

__global__ void scan_offsets(int* blkGt, int* blkEq, int nb){
  if(threadIdx.x==0 && blockIdx.x==0){
    int g=0,e=0;
    for(int j=0;j<nb;j++){ int tg=blkGt[j], te=blkEq[j]; blkGt[j]=g; blkEq[j]=e; g+=tg; e+=te; }
  }
}

__global__ void compact(const float* __restrict__ score, int n,
                        const unsigned* __restrict__ thr, const int* __restrict__ qp,
                        const int* __restrict__ blkGt, const int* __restrict__ blkEq,
                        int* __restrict__ newidx, int* __restrict__ oldidx){
  int i = blockIdx.x*256 + threadIdx.x;
  unsigned vthr = thr[0];
  int q = qp[0];
  int gt=0, eq=0;
  if(i<n){ unsigned o=ordf(score[i]); gt=(o>vthr); eq=(o==vthr); }
  unsigned long long bg=__ballot(gt), be=__ballot(eq);
  int lane=threadIdx.x&63, w=threadIdx.x>>6;
  unsigned long long mask = lane ? (~0ull >> (64-lane)) : 0ull;
  int pg = __popcll(bg & mask), pe = __popcll(be & mask);
  __shared__ int sg[4], se[4];
  if(lane==63){ sg[w]=pg+gt; se[w]=pe+eq; }
  __syncthreads();
  int wg=0,we=0;
  for(int j=0;j<w;j++){ wg+=sg[j]; we+=se[j]; }
  if(i<n){
    int gtp = blkGt[blockIdx.x] + wg + pg;   // exclusive prefix of gt over all i' < i
    int eqp = blkEq[blockIdx.x] + we + pe;   // exclusive prefix of eq over all i' < i
    int sel = gt || (eq && (eqp < q));
    if(sel){
      int pos = gtp + (eqp < q ? eqp : q);
      newidx[i]=pos; oldidx[pos]=i;
    } else newidx[i]=-1;
  }
}

__global__ void gather_scale(const float* __restrict__ hfull, const float* __restrict__ score,
                             const int* __restrict__ oldidx, float* __restrict__ hout,
                             int k, int Fo, int shift){
  long long t = (long long)blockIdx.x*blockDim.x + threadIdx.x;
  int nr = (int)(t >> shift);
  if(nr >= k) return;
  int f = (int)(t & (Fo-1));
  int old = oldidx[nr];
  hout[t] = hfull[(size_t)old*Fo+f] * score[old];
}

__global__ void remap_edges(int* __restrict__ src, int* __restrict__ dst,
                            int* __restrict__ valid, const int* __restrict__ newidx){
  int e = blockIdx.x*blockDim.x + threadIdx.x;
  if(e>=NE) return;
  if(valid[e]){
    int ns=newidx[src[e]], nd=newidx[dst[e]];
    if(ns>=0 && nd>=0){ src[e]=ns; dst[e]=nd; }
    else valid[e]=0;
  }
}

// per-feature max & mean over final nodes; xc[0:256]=max, xc[256:512]=mean
__global__ void pool_kernel(const float* __restrict__ h, int n, float* __restrict__ xc){
  int f = blockIdx.x;
  float mx = -3.402823466e38f, sm=0.f;
  for(int r=threadIdx.x; r<n; r+=blockDim.x){
    float v = h[(size_t)r*256+f];
    mx = fmaxf(mx,v); sm += v;
  }
  __shared__ float smx[4], ssm[4];
  for(int o=32;o;o>>=1){ mx=fmaxf(mx,__shfl_down(mx,o,64)); sm+=__shfl_down(sm,o,64); }
  int lane=threadIdx.x&63, w=threadIdx.x>>6;
  if(lane==0){ smx[w]=mx; ssm[w]=sm; }
  __syncthreads();
  if(threadIdx.x==0){
    for(int j=1;j<4;j++){ mx=fmaxf(mx,smx[j]); sm+=ssm[j]; }
    xc[f]=mx; xc[256+f]=sm/(float)n;
  }
}

__global__ void fc_kernel(const float* __restrict__ xc, const float* __restrict__ fcw,
                          const float* __restrict__ fcb, const float* __restrict__ fc2w,
                          const float* __restrict__ fc2b, float* __restrict__ out){
  __shared__ float x[512];
  for(int i=threadIdx.x;i<512;i+=256) x[i]=xc[i];
  __syncthreads();
  int j=threadIdx.x;
  float a=fcb[j];
  for(int i=0;i<512;i++) a = fmaf(x[i], fcw[(size_t)j*512+i], a);
  a = a>0.f ? a : 0.f;
  float v = a*fc2w[j];
  for(int o=32;o;o>>=1) v += __shfl_down(v,o,64);
  __shared__ float sv[4];
  int lane=threadIdx.x&63, w=threadIdx.x>>6;
  if(lane==0) sv[w]=v;
  __syncthreads();
  if(threadIdx.x==0) out[0]=sv[0]+sv[1]+sv[2]+sv[3]+fc2b[0];
}

extern "C" void kernel_launch(void* const* d_in, const int* in_sizes, int n_in,
                              void* d_out, int out_size, void* d_ws, size_t ws_size,
                              hipStream_t stream) {
  const float* x   = (const float*)d_in[0];
  const int*   ei  = (const int*)d_in[1];
  const float* Wm[4] = {(const float*)d_in[2],(const float*)d_in[5],(const float*)d_in[8],(const float*)d_in[11]};
  const float* bv[4] = {(const float*)d_in[3],(const float*)d_in[6],(const float*)d_in[9],(const float*)d_in[12]};
  const float* pv[4] = {(const float*)d_in[4],(const float*)d_in[7],(const float*)d_in[10],(const float*)d_in[13]};
  const float* fcw  = (const float*)d_in[14];
  const float* fcb  = (const float*)d_in[15];
  const float* fc2w = (const float*)d_in[16];
  const float* fc2b = (const float*)d_in[17];

  // workspace carve-up
  char* base = (char*)d_ws; size_t off=0;
  auto alloc = [&](size_t bytes)->void*{
    void* p = base + off; off += (bytes + 511) & ~(size_t)511; return p;
  };
  int*   s_src  = (int*)  alloc((size_t)NE*4);
  int*   s_dst  = (int*)  alloc((size_t)NE*4);
  int*   s_val  = (int*)  alloc((size_t)NE*4);
  float* enorm  = (float*)alloc((size_t)NE*4);
  float* deg    = (float*)alloc((size_t)NV*4);
  float* score  = (float*)alloc((size_t)NV*4);
  int*   newidx = (int*)  alloc((size_t)NV*4);
  int*   oldidx = (int*)  alloc((size_t)NV*4);
  float* hw     = (float*)alloc((size_t)5243136*4);
  float* agg    = (float*)alloc((size_t)5243136*4);
  float* hbuf   = (float*)alloc((size_t)2621696*4);
  float* pn     = (float*)alloc(64);
  unsigned* thr = (unsigned*)alloc(64);
  int*   qv     = (int*)  alloc(64);
  int*   blkGt  = (int*)  alloc(4096);
  int*   blkEq  = (int*)  alloc(4096);
  float* xc     = (float*)alloc(2048);
  if (off > ws_size) return;  // workspace too small -> fail loudly in validation

  const int ns[5]   = {163842, 81921, 40961, 20481, 10241};
  const int dims[5] = {4, 32, 64, 128, 256};
  const int shf[4]  = {5, 6, 7, 8};

  copy_edges<<<(NE+255)/256,256,0,stream>>>(ei, s_src, s_dst, s_val);

  const float* hin = x;
  for(int l=0;l<4;l++){
    int n=ns[l], k=ns[l+1], Fi=dims[l], Fo=dims[l+1], sh=shf[l];
    long long rbc = (n+15)/16;
    matmul16<<<(unsigned)((rbc*Fo+255)/256),256,0,stream>>>(hin, Wm[l], hw, n, Fi, Fo, sh);
    fill_f32<<<(n+255)/256,256,0,stream>>>(deg, 0.f, n);
    scatter_deg<<<(NE+255)/256,256,0,stream>>>(s_src, s_dst, s_val, deg);
    compute_norm<<<(NE+255)/256,256,0,stream>>>(s_src, s_dst, s_val, deg, enorm);
    long long nf = (long long)n*Fo;
    fill_f32<<<(unsigned)((nf+255)/256),256,0,stream>>>(agg, 0.f, (int)nf);
    scatter_agg<<<(unsigned)((((long long)NE<<sh)+255)/256),256,0,stream>>>(s_src, s_dst, s_val, enorm, hw, agg, Fo, sh);
    finalize<<<(unsigned)((nf+255)/256),256,0,stream>>>(agg, hw, deg, bv[l], n, Fo, sh);
    pnorm_kernel<<<1,64,0,stream>>>(pv[l], Fo, pn);
    score_kernel<<<(n+3)/4,256,0,stream>>>(agg, n, Fo, pv[l], pn, score);
    radix_select<<<1,1024,0,stream>>>(score, n, k, thr, qv);
    int nb = (n+255)/256;
    sel_blockcount<<<nb,256,0,stream>>>(score, n, thr, blkGt, blkEq);
    scan_offsets<<<1,64,0,stream>>>(blkGt, blkEq, nb);
    compact<<<nb,256,0,stream>>>(score, n, thr, qv, blkGt, blkEq, newidx, oldidx);
    gather_scale<<<(unsigned)((((long long)k*Fo)+255)/256),256,0,stream>>>(agg, score, oldidx, hbuf, k, Fo, sh);
    remap_edges<<<(NE+255)/256,256,0,stream>>>(s_src, s_dst, s_val, newidx);
    hin = hbuf;
  }

  pool_kernel<<<256,256,0,stream>>>(hbuf, ns[4], xc);
  fc_kernel<<<1,256,0,stream>>>(xc, fcw, fcb, fc2w, fc2b, (float*)d_out);
}